// Round 3
// baseline (9191.849 us; speedup 1.0000x reference)
//
#include <hip/hip_runtime.h>
#include <hip/hip_bf16.h>
#include <cstdint>
#include <cstddef>

#define B_ALL 256
#define T_SZ  1024

__device__ __forceinline__ float sigmoidf_(float x) { return 1.0f / (1.0f + expf(-x)); }

__device__ __forceinline__ float bf2f_(unsigned short u) {
    union { unsigned int i; float f; } c; c.i = ((unsigned int)u) << 16; return c.f;
}
__device__ __forceinline__ float4 load4bf(const __hip_bfloat16* p) {
    unsigned long long v = *(const unsigned long long*)p;
    float4 f;
    f.x = bf2f_((unsigned short)v);
    f.y = bf2f_((unsigned short)(v >> 16));
    f.z = bf2f_((unsigned short)(v >> 32));
    f.w = bf2f_((unsigned short)(v >> 48));
    return f;
}

// ---------------- conv (causal, k=5) + relu -> X1[b_local][t][64] (bf16) ----------------
__global__ void conv_relu_kernel(const float* __restrict__ x, const float* __restrict__ w,
                                 const float* __restrict__ bias, __hip_bfloat16* __restrict__ out,
                                 int bg0)
{
    int c  = threadIdx.x & 63;
    int tq = threadIdx.x >> 6;
    int t  = blockIdx.x * 4 + tq;
    int b  = blockIdx.y;                       // local batch index
    const float* xb = x + (size_t)(bg0 + b) * T_SZ;
    float s = bias[c];
#pragma unroll
    for (int k = 0; k < 5; ++k) {
        int ti = t - 4 + k;
        float xv = (ti >= 0) ? xb[ti] : 0.0f;
        s = fmaf(w[c * 5 + k], xv, s);
    }
    out[((size_t)b * T_SZ + t) * 64 + c] = __float2bfloat16(fmaxf(s, 0.0f));
}

// ---------------- chunked input-projection GEMM ----------------
// chunk steps s in [t0, t0+Tc), t = dir ? T-1-s : s
// out[dir][(sl*Bg + b)*N + n] = sum_k A[(b*T+t)*K + k] * W[dir][n*K+k] + bias[dir][n]
__global__ __launch_bounds__(256) void proj_kernel(
    const __hip_bfloat16* __restrict__ A, const float* __restrict__ W,
    const float* __restrict__ bias, float* __restrict__ out,
    int K, int N, int lg /*log2 Tc*/, int t0, int Bg)
{
    int dir = blockIdx.z;
    int Tc  = 1 << lg;
    W    += (size_t)dir * N * K;
    bias += (size_t)dir * N;
    out  += (size_t)dir * Tc * Bg * N;

    __shared__ float As[16][68];
    __shared__ float Ws[16][68];

    int tid = threadIdx.x;
    int tx = tid & 15, ty = tid >> 4;
    int m0 = blockIdx.x * 64;     // m = b*Tc + tl
    int n0 = blockIdx.y * 64;

    float acc[4][4];
#pragma unroll
    for (int i = 0; i < 4; i++)
#pragma unroll
        for (int j = 0; j < 4; j++) acc[i][j] = 0.f;

    int li = tid >> 2;        // 0..63
    int lk = (tid & 3) * 4;   // 0,4,8,12

    int mi = m0 + li;
    int bA = mi >> lg, tlA = mi & (Tc - 1);
    int tA = dir ? (T_SZ - 1 - (t0 + tlA)) : (t0 + tlA);
    const __hip_bfloat16* arow = A + ((size_t)bA * T_SZ + tA) * K;
    const float*          wrow = W + (size_t)(n0 + li) * K;

    for (int k0 = 0; k0 < K; k0 += 16) {
        float4 av = load4bf(&arow[k0 + lk]);
        float4 wv = *(const float4*)&wrow[k0 + lk];
        As[lk + 0][li] = av.x; As[lk + 1][li] = av.y; As[lk + 2][li] = av.z; As[lk + 3][li] = av.w;
        Ws[lk + 0][li] = wv.x; Ws[lk + 1][li] = wv.y; Ws[lk + 2][li] = wv.z; Ws[lk + 3][li] = wv.w;
        __syncthreads();
#pragma unroll
        for (int kk = 0; kk < 16; ++kk) {
            float4 a4 = *(const float4*)&As[kk][ty * 4];
            float4 w4 = *(const float4*)&Ws[kk][tx * 4];
            float ar[4] = {a4.x, a4.y, a4.z, a4.w};
            float wr[4] = {w4.x, w4.y, w4.z, w4.w};
#pragma unroll
            for (int i = 0; i < 4; i++)
#pragma unroll
                for (int j = 0; j < 4; j++)
                    acc[i][j] = fmaf(ar[i], wr[j], acc[i][j]);
        }
        __syncthreads();
    }
#pragma unroll
    for (int i = 0; i < 4; i++) {
        int m = m0 + ty * 4 + i;
        int bO = m >> lg, tlO = m & (Tc - 1);
        int n = n0 + tx * 4;
        float4 o;
        o.x = acc[i][0] + bias[n + 0];
        o.y = acc[i][1] + bias[n + 1];
        o.z = acc[i][2] + bias[n + 2];
        o.w = acc[i][3] + bias[n + 3];
        *(float4*)&out[((size_t)tlO * Bg + bO) * N + n] = o;
    }
}

// ---------------- LSTM recurrence (chunked, W_hh register-resident) ----------------
// Block = NB local batch rows, one direction, blockDim = 4H.
// xw chunk layout: [dir][Tc][Bg][4H] (bias folded). w_hh raw [dir][4H][H].
template <int H, int NB, bool WRITE_Y>
__global__ __launch_bounds__(4 * H) void lstm_rec_kernel(
    const float* __restrict__ xw, const float* __restrict__ w_hh,
    __hip_bfloat16* __restrict__ y, float* __restrict__ lastOut,
    float* __restrict__ Hst, float* __restrict__ Cst,
    int Bg, int Tc, int step0, int zeroInit, int writeLast)
{
    constexpr int FH = 4 * H;
    int dir = blockIdx.y;
    int b0  = blockIdx.x * NB;
    int g   = threadIdx.x;

    __shared__ float hs[NB][H];
    __shared__ float gs[NB][FH];

    float wreg[H];
    {
        const float* wrow = w_hh + ((size_t)dir * FH + g) * H;
#pragma unroll
        for (int k = 0; k < H; k += 4) {
            float4 w4 = *(const float4*)&wrow[k];
            wreg[k] = w4.x; wreg[k + 1] = w4.y; wreg[k + 2] = w4.z; wreg[k + 3] = w4.w;
        }
    }

    int bb = g / H;
    int hh = g % H;
    float c = 0.f;
    if (g < NB * H) {
        if (zeroInit) {
            hs[bb][hh] = 0.f;
        } else {
            hs[bb][hh] = Hst[((size_t)dir * Bg + b0 + bb) * H + hh];
            c          = Cst[((size_t)dir * Bg + b0 + bb) * H + hh];
        }
    }
    __syncthreads();

    const float* xwb = xw + ((size_t)dir * Tc * Bg + b0) * FH + g;

    for (int sl = 0; sl < Tc; ++sl) {
        int s = step0 + sl;
        int t = dir ? (T_SZ - 1 - s) : s;
        const float* xp = xwb + (size_t)sl * Bg * FH;
        float xv[NB];
#pragma unroll
        for (int r = 0; r < NB; ++r) xv[r] = xp[r * FH];

        float a[NB];
#pragma unroll
        for (int r = 0; r < NB; ++r) a[r] = 0.f;

#pragma unroll
        for (int k = 0; k < H; k += 4) {
            float4 hv[NB];
#pragma unroll
            for (int r = 0; r < NB; ++r) hv[r] = *(const float4*)&hs[r][k];
#pragma unroll
            for (int r = 0; r < NB; ++r) {
                a[r] = fmaf(wreg[k + 0], hv[r].x, a[r]);
                a[r] = fmaf(wreg[k + 1], hv[r].y, a[r]);
                a[r] = fmaf(wreg[k + 2], hv[r].z, a[r]);
                a[r] = fmaf(wreg[k + 3], hv[r].w, a[r]);
            }
        }
#pragma unroll
        for (int r = 0; r < NB; ++r) gs[r][g] = a[r] + xv[r];
        __syncthreads();

        if (g < NB * H) {
            float iv = gs[bb][hh];
            float fv = gs[bb][H + hh];
            float gv = gs[bb][2 * H + hh];
            float ov = gs[bb][3 * H + hh];
            c = sigmoidf_(fv) * c + sigmoidf_(iv) * tanhf(gv);
            float hval = sigmoidf_(ov) * tanhf(c);
            hs[bb][hh] = hval;
            if (WRITE_Y) {
                y[(((size_t)(b0 + bb)) * T_SZ + t) * (2 * H) + dir * H + hh] = __float2bfloat16(hval);
            } else if (writeLast && sl == Tc - 1) {
                lastOut[(b0 + bb) * 128 + hh] = hval;
            }
        }
        __syncthreads();
    }

    if (g < NB * H) {
        Hst[((size_t)dir * Bg + b0 + bb) * H + hh] = hs[bb][hh];
        Cst[((size_t)dir * Bg + b0 + bb) * H + hh] = c;
    }
}

// ---------------- layer-3 backward: exactly one step from zero state ----------------
__global__ __launch_bounds__(256) void lstm3_bwd_kernel(
    const __hip_bfloat16* __restrict__ y2, const float* __restrict__ w_ih3,
    const float* __restrict__ b3, float* __restrict__ H3)
{
    int b = blockIdx.x, g = threadIdx.x;   // local batch
    __shared__ float xr[256];
    __shared__ float gsh[256];
    xr[g] = __bfloat162float(y2[((size_t)b * T_SZ + (T_SZ - 1)) * 256 + g]);
    __syncthreads();
    const float* wr = w_ih3 + (size_t)256 * 256 + (size_t)g * 256;  // dir 1
    float acc = b3[256 + g];
#pragma unroll 4
    for (int k = 0; k < 256; k++) acc = fmaf(wr[k], xr[k], acc);
    gsh[g] = acc;
    __syncthreads();
    if (g < 64) {
        float iv = gsh[g], gv = gsh[128 + g], ov = gsh[192 + g];
        float ct = sigmoidf_(iv) * tanhf(gv);   // c0 = 0 -> forget term vanishes
        float hv = sigmoidf_(ov) * tanhf(ct);
        H3[b * 128 + 64 + g] = hv;
    }
}

// ---------------- FC ----------------
__global__ void fc_kernel(const float* __restrict__ in, const float* __restrict__ W,
                          const float* __restrict__ bias, float* __restrict__ out,
                          int K, int N, int doRelu)
{
    int b = blockIdx.x;
    int g = threadIdx.x;
    extern __shared__ float xr[];
    for (int i = g; i < K; i += blockDim.x) xr[i] = in[(size_t)b * K + i];
    __syncthreads();
    if (g < N) {
        const float* wr = W + (size_t)g * K;
        float acc = bias[g];
        for (int k = 0; k < K; k++) acc = fmaf(wr[k], xr[k], acc);
        if (doRelu) acc = fmaxf(acc, 0.f);
        out[(size_t)b * N + g] = acc;
    }
}

extern "C" void kernel_launch(void* const* d_in, const int* in_sizes, int n_in,
                              void* d_out, int out_size, void* d_ws, size_t ws_size,
                              hipStream_t stream)
{
    (void)in_sizes; (void)n_in; (void)out_size;
    const float* x      = (const float*)d_in[0];
    const float* conv_w = (const float*)d_in[1];
    const float* conv_b = (const float*)d_in[2];
    const float* w_ih1  = (const float*)d_in[3];
    const float* w_hh1  = (const float*)d_in[4];
    const float* b1     = (const float*)d_in[5];
    const float* w_ih2  = (const float*)d_in[6];
    const float* w_hh2  = (const float*)d_in[7];
    const float* b2     = (const float*)d_in[8];
    const float* w_ih3  = (const float*)d_in[9];
    const float* w_hh3  = (const float*)d_in[10];
    const float* b3     = (const float*)d_in[11];
    const float* fc1_w  = (const float*)d_in[12];
    const float* fc1_b  = (const float*)d_in[13];
    const float* fc2_w  = (const float*)d_in[14];
    const float* fc2_b  = (const float*)d_in[15];
    const float* fc3_w  = (const float*)d_in[16];
    const float* fc3_b  = (const float*)d_in[17];
    const float* fc4_w  = (const float*)d_in[18];
    const float* fc4_b  = (const float*)d_in[19];
    float* out = (float*)d_out;
    char*  base = (char*)d_ws;

    const size_t MB = 1ull << 20;

    // footprint(S, Tc) = 2 * Ybytes + XWbytes + 2MB small
    auto need = [&](int s, int tc) -> size_t {
        size_t Bg = B_ALL / s;
        size_t YB = Bg * T_SZ * 256 * 2;                 // bf16 Y buffer
        size_t XW = (size_t)tc * Bg * 512 * 4 * 2;       // fp32 chunk, 2 dirs
        return 2 * YB + XW + 2 * MB;
    };

    int S = 8;
    for (int s : {1, 2, 4, 8}) {
        if (need(s, 16) <= ws_size) { S = s; break; }
    }
    int Tc = 16;
    while (Tc < 256 && need(S, Tc * 2) <= ws_size) Tc <<= 1;
    int lg = 0; while ((1 << lg) < Tc) lg++;
    int NC = T_SZ / Tc;

    int Bg = B_ALL / S;
    size_t YB = (size_t)Bg * T_SZ * 256 * 2;
    __hip_bfloat16* Y1 = (__hip_bfloat16*)base;
    __hip_bfloat16* Y2 = (__hip_bfloat16*)(base + YB);
    __hip_bfloat16* X1 = Y2;                             // aliased: X1 dead before Y2 written
    float* XWc = (float*)(base + 2 * YB);
    float* sm  = (float*)(base + 2 * YB + (size_t)Tc * Bg * 512 * 4 * 2);
    float* Hs = sm;                   // 2*Bg*128
    float* Cs = Hs + 2 * Bg * 128;
    float* H3 = Cs + 2 * Bg * 128;    // Bg*128
    float* F1 = H3 + Bg * 128;        // Bg*512
    float* F2 = F1 + Bg * 512;        // Bg*256
    float* F3 = F2 + Bg * 256;        // Bg*128

    for (int sp = 0; sp < S; ++sp) {
        int bg0 = sp * Bg;

        conv_relu_kernel<<<dim3(T_SZ / 4, Bg), 256, 0, stream>>>(x, conv_w, conv_b, X1, bg0);

        // layer 1 (D=64, H=128) : X1 -> Y1
        for (int ci = 0; ci < NC; ++ci) {
            proj_kernel<<<dim3(Bg * Tc / 64, 512 / 64, 2), 256, 0, stream>>>(
                X1, w_ih1, b1, XWc, 64, 512, lg, ci * Tc, Bg);
            if (Bg >= 256)
                lstm_rec_kernel<128, 2, true><<<dim3(Bg / 2, 2), 512, 0, stream>>>(
                    XWc, w_hh1, Y1, nullptr, Hs, Cs, Bg, Tc, ci * Tc, ci == 0, 0);
            else
                lstm_rec_kernel<128, 1, true><<<dim3(Bg, 2), 512, 0, stream>>>(
                    XWc, w_hh1, Y1, nullptr, Hs, Cs, Bg, Tc, ci * Tc, ci == 0, 0);
        }
        // layer 2 (D=256, H=128) : Y1 -> Y2 (overwrites X1 region; X1 is dead)
        for (int ci = 0; ci < NC; ++ci) {
            proj_kernel<<<dim3(Bg * Tc / 64, 512 / 64, 2), 256, 0, stream>>>(
                Y1, w_ih2, b2, XWc, 256, 512, lg, ci * Tc, Bg);
            if (Bg >= 256)
                lstm_rec_kernel<128, 2, true><<<dim3(Bg / 2, 2), 512, 0, stream>>>(
                    XWc, w_hh2, Y2, nullptr, Hs, Cs, Bg, Tc, ci * Tc, ci == 0, 0);
            else
                lstm_rec_kernel<128, 1, true><<<dim3(Bg, 2), 512, 0, stream>>>(
                    XWc, w_hh2, Y2, nullptr, Hs, Cs, Bg, Tc, ci * Tc, ci == 0, 0);
        }
        // layer 3 (D=256, H=64): forward full scan (final h only) + backward single step
        for (int ci = 0; ci < NC; ++ci) {
            proj_kernel<<<dim3(Bg * Tc / 64, 256 / 64, 1), 256, 0, stream>>>(
                Y2, w_ih3, b3, XWc, 256, 256, lg, ci * Tc, Bg);
            lstm_rec_kernel<64, 1, false><<<dim3(Bg, 1), 256, 0, stream>>>(
                XWc, w_hh3, nullptr, H3, Hs, Cs, Bg, Tc, ci * Tc, ci == 0, ci == NC - 1);
        }
        lstm3_bwd_kernel<<<Bg, 256, 0, stream>>>(Y2, w_ih3, b3, H3);

        // FC head (local rows), final store to global out rows [bg0, bg0+Bg)
        fc_kernel<<<Bg, 512, 128 * 4, stream>>>(H3, fc1_w, fc1_b, F1, 128, 512, 1);
        fc_kernel<<<Bg, 256, 512 * 4, stream>>>(F1, fc2_w, fc2_b, F2, 512, 256, 1);
        fc_kernel<<<Bg, 128, 256 * 4, stream>>>(F2, fc3_w, fc3_b, F3, 256, 128, 1);
        fc_kernel<<<Bg, 64, 128 * 4, stream>>>(F3, fc4_w, fc4_b, out + (size_t)bg0 * 2, 128, 2, 0);
    }
}